// Round 1
// baseline (626.798 us; speedup 1.0000x reference)
//
#include <hip/hip_runtime.h>
#include <hip/hip_bf16.h>

typedef unsigned short bfu;
typedef __attribute__((ext_vector_type(8))) short short8;
typedef __attribute__((ext_vector_type(4))) float f32x4;

__device__ __forceinline__ bfu f2bf(float f) {
  return __builtin_bit_cast(bfu, __float2bfloat16(f));
}

__device__ __forceinline__ void gld16(const void* g, void* l) {
  __builtin_amdgcn_global_load_lds(
      (const __attribute__((address_space(1))) void*)g,
      (__attribute__((address_space(3))) void*)l, 16, 0, 0);
}

// ---------------- weight transpose + bf16 cast: WT[n][k] = W[k][n] ----------
__global__ void transpose_w(const float* __restrict__ W, bfu* __restrict__ WT,
                            int K, int N) {
  int idx = blockIdx.x * 256 + threadIdx.x;
  if (idx >= K * N) return;
  int k = idx / N, n = idx - k * N;
  WT[(size_t)n * K + k] = f2bf(W[idx]);
}

// ---------------- LayerNorm: one wave per row of 384 ------------------------
__launch_bounds__(256)
__global__ void ln_kernel(const float* __restrict__ in, const float* __restrict__ g,
                          const float* __restrict__ be, bfu* __restrict__ out) {
  const int wv = threadIdx.x >> 6, ln = threadIdx.x & 63;
  const size_t row = (size_t)blockIdx.x * 4 + wv;
  const float* p = in + row * 384;
  float v[6], s = 0.f, ss = 0.f;
#pragma unroll
  for (int i = 0; i < 6; i++) { v[i] = p[i * 64 + ln]; s += v[i]; ss += v[i] * v[i]; }
#pragma unroll
  for (int m = 1; m < 64; m <<= 1) { s += __shfl_xor(s, m); ss += __shfl_xor(ss, m); }
  const float mean = s * (1.f / 384.f);
  const float rs = rsqrtf(ss * (1.f / 384.f) - mean * mean + 1e-5f);
  bfu* q = out + row * 384;
#pragma unroll
  for (int i = 0; i < 6; i++) {
    const int c = i * 64 + ln;
    q[c] = f2bf((v[i] - mean) * rs * g[c] + be[c]);
  }
}

// ---------------- GEMM: C[M,N] = A[M,K](bf16) @ BT[N,K](bf16)^T -------------
// 128x128 tile, BK=32, 4 waves (2x2), 16 MFMA/K-step, global_load_lds staging.
template <int BIAS, int RELU, int RES, int OUTBF>
__launch_bounds__(256)
__global__ void gemm_kernel(const bfu* __restrict__ A, const bfu* __restrict__ Bt,
                            const float* __restrict__ bias, const float* __restrict__ res,
                            void* __restrict__ Cout, int N, int K) {
  __shared__ bfu a_sm[128 * 32];
  __shared__ bfu b_sm[128 * 32];
  const int tid = threadIdx.x;
  const int wv = tid >> 6, ln = tid & 63;
  const int ntn = N >> 7;
  const int bm = blockIdx.x / ntn, bn = blockIdx.x - bm * ntn;
  const int m0 = bm << 7, n0 = bn << 7;
  const int wr = wv >> 1, wc = wv & 1;
  const int fr = ln & 15, fc = (ln >> 4) << 3;

  f32x4 acc[4][4];
#pragma unroll
  for (int i = 0; i < 4; i++)
#pragma unroll
    for (int j = 0; j < 4; j++) acc[i][j] = f32x4{0.f, 0.f, 0.f, 0.f};

  for (int kt = 0; kt < K; kt += 32) {
    __syncthreads();
#pragma unroll
    for (int i = 0; i < 2; ++i) {
      const int bo = wv * 2048 + i * 1024 + ln * 16;  // byte offset in 8KB tile
      const int r = bo >> 6;                          // 64B (32 bf16) per row
      const int c = (bo & 63) >> 1;
      gld16(A  + (size_t)(m0 + r) * K + kt + c, (char*)a_sm + wv * 2048 + i * 1024);
      gld16(Bt + (size_t)(n0 + r) * K + kt + c, (char*)b_sm + wv * 2048 + i * 1024);
    }
    __syncthreads();
    short8 af[4], bfr[4];
#pragma unroll
    for (int mi = 0; mi < 4; mi++)
      af[mi] = *(const short8*)&a_sm[(wr * 64 + mi * 16 + fr) * 32 + fc];
#pragma unroll
    for (int ni = 0; ni < 4; ni++)
      bfr[ni] = *(const short8*)&b_sm[(wc * 64 + ni * 16 + fr) * 32 + fc];
#pragma unroll
    for (int mi = 0; mi < 4; mi++)
#pragma unroll
      for (int ni = 0; ni < 4; ni++)
        acc[mi][ni] = __builtin_amdgcn_mfma_f32_16x16x32_bf16(af[mi], bfr[ni], acc[mi][ni], 0, 0, 0);
  }

#pragma unroll
  for (int mi = 0; mi < 4; mi++) {
#pragma unroll
    for (int ni = 0; ni < 4; ni++) {
      const int row = m0 + wr * 64 + mi * 16 + ((ln >> 4) << 2);
      const int col = n0 + wc * 64 + ni * 16 + fr;
      float bv = 0.f;
      if (BIAS) bv = bias[col];
#pragma unroll
      for (int r = 0; r < 4; r++) {
        float v = acc[mi][ni][r] + bv;
        if (RELU) v = fmaxf(v, 0.f);
        const size_t idx = (size_t)(row + r) * N + col;
        if (RES) v += res[idx];
        if (OUTBF) ((bfu*)Cout)[idx] = f2bf(v);
        else       ((float*)Cout)[idx] = v;
      }
    }
  }
}

// ---------------- fused causal attention: 1 block per (b,h), 8 waves --------
#define KPAD 72
#define VPAD 264
#define PPAD 264

__launch_bounds__(512)
__global__ void attn_kernel(const bfu* __restrict__ qb, const bfu* __restrict__ kb,
                            const bfu* __restrict__ vb, bfu* __restrict__ ob) {
  __shared__ bfu k_sm[256 * KPAD];
  __shared__ bfu vt_sm[64 * VPAD];
  __shared__ bfu p_sm[8 * 16 * PPAD];
  const int b = blockIdx.x / 6, h = blockIdx.x - b * 6;
  const int tid = threadIdx.x;
  const int wv = tid >> 6, ln = tid & 63;
  const int fr = ln & 15, fc = (ln >> 4) << 3;
  const size_t rowbase = (size_t)b * 256 * 384 + h * 64;

  {  // stage K row-major (padded) and V transposed (padded)
    const int row = tid >> 1;
    const int dh = (tid & 1) << 5;
    const bfu* kg = kb + rowbase + (size_t)row * 384 + dh;
    const bfu* vg = vb + rowbase + (size_t)row * 384 + dh;
#pragma unroll
    for (int i = 0; i < 4; i++) {
      short8 t8 = *(const short8*)(kg + i * 8);
      *(short8*)&k_sm[row * KPAD + dh + i * 8] = t8;
      short8 v8 = *(const short8*)(vg + i * 8);
#pragma unroll
      for (int j = 0; j < 8; j++)
        vt_sm[(dh + i * 8 + j) * VPAD + row] = (bfu)v8[j];
    }
  }
  __syncthreads();

  bfu* pw = &p_sm[wv * 16 * PPAD];
  const int rq = (ln >> 4) << 2;  // C-layout row offset within 16-row subtile

#pragma unroll
  for (int si = 0; si < 2; ++si) {
    const int s = si ? (15 - wv) : wv;    // balanced causal work: {w, 15-w}
    const int qr0 = s << 4;
    const int nf = s + 1;                 // kv fragments needed (causal)
    short8 aq[2];
#pragma unroll
    for (int dc = 0; dc < 2; dc++)
      aq[dc] = *(const short8*)(qb + rowbase + (size_t)(qr0 + fr) * 384 + dc * 32 + fc);

    f32x4 sacc[16];
#pragma unroll
    for (int f = 0; f < 16; f++) sacc[f] = f32x4{0.f, 0.f, 0.f, 0.f};
#pragma unroll
    for (int f = 0; f < 16; f++) if (f < nf) {
#pragma unroll
      for (int dc = 0; dc < 2; dc++) {
        short8 kf = *(const short8*)&k_sm[(f * 16 + fr) * KPAD + dc * 32 + fc];
        sacc[f] = __builtin_amdgcn_mfma_f32_16x16x32_bf16(aq[dc], kf, sacc[f], 0, 0, 0);
      }
    }
    // scale + causal mask + row max
    float mr[4] = {-3e38f, -3e38f, -3e38f, -3e38f};
#pragma unroll
    for (int f = 0; f < 16; f++) if (f < nf) {
#pragma unroll
      for (int r = 0; r < 4; r++) {
        float sv = sacc[f][r] * 0.125f;
        if (f * 16 + fr > qr0 + rq + r) sv = -3e38f;
        sacc[f][r] = sv;
        mr[r] = fmaxf(mr[r], sv);
      }
    }
#pragma unroll
    for (int msk = 1; msk < 16; msk <<= 1) {
#pragma unroll
      for (int r = 0; r < 4; r++) mr[r] = fmaxf(mr[r], __shfl_xor(mr[r], msk));
    }
    float ls[4] = {0.f, 0.f, 0.f, 0.f};
#pragma unroll
    for (int f = 0; f < 16; f++) if (f < nf) {
#pragma unroll
      for (int r = 0; r < 4; r++) {
        float p = __expf(sacc[f][r] - mr[r]);
        sacc[f][r] = p;
        ls[r] += p;
      }
    }
#pragma unroll
    for (int msk = 1; msk < 16; msk <<= 1) {
#pragma unroll
      for (int r = 0; r < 4; r++) ls[r] += __shfl_xor(ls[r], msk);
    }
    // write P (bf16) to per-wave LDS in A-fragment-readable layout
#pragma unroll
    for (int f = 0; f < 16; f++) if (f < nf) {
#pragma unroll
      for (int r = 0; r < 4; r++)
        pw[(rq + r) * PPAD + f * 16 + fr] = f2bf(sacc[f][r]);
    }
    if (nf & 1) {
#pragma unroll
      for (int r = 0; r < 4; r++) pw[(rq + r) * PPAD + nf * 16 + fr] = 0;
    }
    // PV
    f32x4 oc[4];
#pragma unroll
    for (int n = 0; n < 4; n++) oc[n] = f32x4{0.f, 0.f, 0.f, 0.f};
    const int kcs = (nf + 1) >> 1;
#pragma unroll
    for (int kc = 0; kc < 8; ++kc) if (kc < kcs) {
      short8 pa = *(const short8*)&pw[fr * PPAD + kc * 32 + fc];
#pragma unroll
      for (int n = 0; n < 4; n++) {
        short8 vf = *(const short8*)&vt_sm[(n * 16 + fr) * VPAD + kc * 32 + fc];
        oc[n] = __builtin_amdgcn_mfma_f32_16x16x32_bf16(pa, vf, oc[n], 0, 0, 0);
      }
    }
    float inv[4];
#pragma unroll
    for (int r = 0; r < 4; r++) inv[r] = 1.f / ls[r];
#pragma unroll
    for (int n = 0; n < 4; n++) {
#pragma unroll
      for (int r = 0; r < 4; r++)
        ob[rowbase + (size_t)(qr0 + rq + r) * 384 + n * 16 + fr] = f2bf(oc[n][r] * inv[r]);
    }
  }
}

// ---------------- orchestration ---------------------------------------------
extern "C" void kernel_launch(void* const* d_in, const int* in_sizes, int n_in,
                              void* d_out, int out_size, void* d_ws, size_t ws_size,
                              hipStream_t stream) {
  const float* x   = (const float*)d_in[0];
  const float* Wq  = (const float*)d_in[1];
  const float* Wk  = (const float*)d_in[2];
  const float* Wv  = (const float*)d_in[3];
  const float* Wo  = (const float*)d_in[4];
  const float* bo  = (const float*)d_in[5];
  const float* W1  = (const float*)d_in[6];
  const float* b1  = (const float*)d_in[7];
  const float* W2  = (const float*)d_in[8];
  const float* b2  = (const float*)d_in[9];
  const float* g1  = (const float*)d_in[10];
  const float* be1 = (const float*)d_in[11];
  const float* g2  = (const float*)d_in[12];
  const float* be2 = (const float*)d_in[13];
  float* out = (float*)d_out;
  char* ws = (char*)d_ws;

  // workspace layout (bytes); phases strictly ordered on the stream
  bfu* wqT = (bfu*)(ws + 0);
  bfu* wkT = (bfu*)(ws + 294912);
  bfu* wvT = (bfu*)(ws + 589824);
  bfu* woT = (bfu*)(ws + 884736);
  bfu* w1T = (bfu*)(ws + 1179648);
  bfu* w2T = (bfu*)(ws + 2359296);
  char* R1 = ws + 3538944;              // 50.3 MB: h -> attn -> h2
  char* R2 = ws + 3538944 + 50331648;   // 201.3 MB: q,k,v -> y -> a
  bfu*   hb    = (bfu*)R1;
  bfu*   qbuf  = (bfu*)R2;
  bfu*   kbuf  = (bfu*)(R2 + 50331648);
  bfu*   vbuf  = (bfu*)(R2 + 100663296);
  bfu*   attnb = (bfu*)R1;
  float* yb    = (float*)R2;
  bfu*   h2b   = (bfu*)R1;
  bfu*   ab    = (bfu*)R2;

  // 1) weights -> bf16 transposed
  transpose_w<<<576, 256, 0, stream>>>(Wq, wqT, 384, 384);
  transpose_w<<<576, 256, 0, stream>>>(Wk, wkT, 384, 384);
  transpose_w<<<576, 256, 0, stream>>>(Wv, wvT, 384, 384);
  transpose_w<<<576, 256, 0, stream>>>(Wo, woT, 384, 384);
  transpose_w<<<2304, 256, 0, stream>>>(W1, w1T, 384, 1536);
  transpose_w<<<2304, 256, 0, stream>>>(W2, w2T, 1536, 384);

  // 2) LN1
  ln_kernel<<<16384, 256, 0, stream>>>(x, g1, be1, hb);

  // 3) QKV GEMMs (bf16 out)
  gemm_kernel<0, 0, 0, 1><<<1536, 256, 0, stream>>>(hb, wqT, nullptr, nullptr, qbuf, 384, 384);
  gemm_kernel<0, 0, 0, 1><<<1536, 256, 0, stream>>>(hb, wkT, nullptr, nullptr, kbuf, 384, 384);
  gemm_kernel<0, 0, 0, 1><<<1536, 256, 0, stream>>>(hb, wvT, nullptr, nullptr, vbuf, 384, 384);

  // 4) fused causal attention
  attn_kernel<<<1536, 512, 0, stream>>>(qbuf, kbuf, vbuf, attnb);

  // 5) output projection + bias + residual(x) -> y (fp32)
  gemm_kernel<1, 0, 1, 0><<<1536, 256, 0, stream>>>(attnb, woT, bo, x, yb, 384, 384);

  // 6) LN2
  ln_kernel<<<16384, 256, 0, stream>>>(yb, g2, be2, h2b);

  // 7) FFN
  gemm_kernel<1, 1, 0, 1><<<6144, 256, 0, stream>>>(h2b, w1T, b1, nullptr, ab, 1536, 384);
  gemm_kernel<1, 0, 1, 0><<<1536, 256, 0, stream>>>(ab, w2T, b2, x, out, 384, 1536);
}

// Round 2
// 537.777 us; speedup vs baseline: 1.1655x; 1.1655x over previous
//
#include <hip/hip_runtime.h>
#include <hip/hip_bf16.h>

typedef unsigned short bfu;
typedef __attribute__((ext_vector_type(8))) short short8;
typedef __attribute__((ext_vector_type(4))) float f32x4;

__device__ __forceinline__ bfu f2bf(float f) {
  return __builtin_bit_cast(bfu, __float2bfloat16(f));
}

__device__ __forceinline__ void gld16(const void* g, void* l) {
  __builtin_amdgcn_global_load_lds(
      (const __attribute__((address_space(1))) void*)g,
      (__attribute__((address_space(3))) void*)l, 16, 0, 0);
}

// ---------------- weight transpose + bf16 cast: WT[n][k] = W[k][n] ----------
__global__ void transpose_w(const float* __restrict__ W, bfu* __restrict__ WT,
                            int K, int N) {
  int idx = blockIdx.x * 256 + threadIdx.x;
  if (idx >= K * N) return;
  int k = idx / N, n = idx - k * N;
  WT[(size_t)n * K + k] = f2bf(W[idx]);
}

// ---------------- LayerNorm: one wave per row of 384 ------------------------
__launch_bounds__(256)
__global__ void ln_kernel(const float* __restrict__ in, const float* __restrict__ g,
                          const float* __restrict__ be, bfu* __restrict__ out) {
  const int wv = threadIdx.x >> 6, ln = threadIdx.x & 63;
  const size_t row = (size_t)blockIdx.x * 4 + wv;
  const float* p = in + row * 384;
  float v[6], s = 0.f, ss = 0.f;
#pragma unroll
  for (int i = 0; i < 6; i++) { v[i] = p[i * 64 + ln]; s += v[i]; ss += v[i] * v[i]; }
#pragma unroll
  for (int m = 1; m < 64; m <<= 1) { s += __shfl_xor(s, m); ss += __shfl_xor(ss, m); }
  const float mean = s * (1.f / 384.f);
  const float rs = rsqrtf(ss * (1.f / 384.f) - mean * mean + 1e-5f);
  bfu* q = out + row * 384;
#pragma unroll
  for (int i = 0; i < 6; i++) {
    const int c = i * 64 + ln;
    q[c] = f2bf((v[i] - mean) * rs * g[c] + be[c]);
  }
}

// ---------------- GEMM: C[M,N] = A[M,K](bf16) @ BT[N,K](bf16)^T -------------
// 128x128 tile, BK=32, 4 waves (2x2), double-buffered global_load_lds staging,
// one barrier per K-step (prefetch next tile before compute), XCD swizzle.
template <int BIAS, int RELU, int OUTBF>
__launch_bounds__(256)
__global__ void gemm_kernel(const bfu* __restrict__ A, const bfu* __restrict__ Bt,
                            const float* __restrict__ bias,
                            void* __restrict__ Cout, int N, int K, int ntn) {
  __shared__ bfu a_sm[2][128 * 32];
  __shared__ bfu b_sm[2][128 * 32];
  const int tid = threadIdx.x;
  const int wv = tid >> 6, ln = tid & 63;
  // XCD-aware swizzle (grid % 8 == 0 for all call sites)
  const int cpx = gridDim.x >> 3;
  const int wg = (blockIdx.x & 7) * cpx + (blockIdx.x >> 3);
  const int bm = wg / ntn, bn = wg - bm * ntn;
  const int m0 = bm << 7, n0 = bn << 7;
  const int wr = wv >> 1, wc = wv & 1;
  const int fr = ln & 15, fc = (ln >> 4) << 3;

  f32x4 acc[4][4];
#pragma unroll
  for (int i = 0; i < 4; i++)
#pragma unroll
    for (int j = 0; j < 4; j++) acc[i][j] = f32x4{0.f, 0.f, 0.f, 0.f};

  auto stage = [&](int buf, int kt) {
#pragma unroll
    for (int i = 0; i < 2; ++i) {
      const int c = wv * 2 + i;                    // chunk 0..7 (1 KB each)
      const int r = (c << 4) + (ln >> 2);          // 16 rows per chunk
      const int col = kt * 32 + ((ln & 3) << 3);
      gld16(A  + (size_t)(m0 + r) * K + col, (char*)a_sm[buf] + c * 1024);
      gld16(Bt + (size_t)(n0 + r) * K + col, (char*)b_sm[buf] + c * 1024);
    }
  };

  stage(0, 0);
  __syncthreads();
  const int nk = K >> 5;
  for (int kt = 0; kt < nk; ++kt) {
    const int cur = kt & 1;
    if (kt + 1 < nk) stage(cur ^ 1, kt + 1);
    short8 af[4], bfr[4];
#pragma unroll
    for (int mi = 0; mi < 4; mi++)
      af[mi] = *(const short8*)&a_sm[cur][(wr * 64 + mi * 16 + fr) * 32 + fc];
#pragma unroll
    for (int ni = 0; ni < 4; ni++)
      bfr[ni] = *(const short8*)&b_sm[cur][(wc * 64 + ni * 16 + fr) * 32 + fc];
#pragma unroll
    for (int mi = 0; mi < 4; mi++)
#pragma unroll
      for (int ni = 0; ni < 4; ni++)
        acc[mi][ni] = __builtin_amdgcn_mfma_f32_16x16x32_bf16(af[mi], bfr[ni], acc[mi][ni], 0, 0, 0);
    __syncthreads();
  }

#pragma unroll
  for (int mi = 0; mi < 4; mi++) {
#pragma unroll
    for (int ni = 0; ni < 4; ni++) {
      const int row = m0 + wr * 64 + mi * 16 + ((ln >> 4) << 2);
      const int col = n0 + wc * 64 + ni * 16 + fr;
      float bv = 0.f;
      if (BIAS) bv = bias[col];
#pragma unroll
      for (int r = 0; r < 4; r++) {
        float v = acc[mi][ni][r] + bv;
        if (RELU) v = fmaxf(v, 0.f);
        const size_t idx = (size_t)(row + r) * N + col;
        if (OUTBF) ((bfu*)Cout)[idx] = f2bf(v);
        else       ((float*)Cout)[idx] = v;
      }
    }
  }
}

// ---------------- full-row GEMM: C[M,384] = A[M,K] @ Bt[384,K]^T ------------
// BM=128, BN=384 (whole row in one block), 8 waves (2x4, 64x96 each), BK=32,
// double-buffered. Epilogue: +bias +residual, then LN (LN=1, bf16 out) or
// plain fp32 out (LN=0).
template <int LN>
__launch_bounds__(512)
__global__ void row_gemm(const bfu* __restrict__ A, const bfu* __restrict__ Bt,
                         const float* __restrict__ bias, const float* __restrict__ res,
                         const float* __restrict__ g, const float* __restrict__ be,
                         void* __restrict__ Cout, int K) {
  __shared__ bfu a_sm[2][128 * 32];
  __shared__ bfu b_sm[2][384 * 32];
  __shared__ float lnp[4][128][2];
  const int tid = threadIdx.x;
  const int wv = tid >> 6, ln = tid & 63;
  const int wr = wv >> 2, wc = wv & 3;          // 2 x 4 wave grid
  const int fr = ln & 15, fc = (ln >> 4) << 3;
  const int m0 = blockIdx.x << 7;

  f32x4 acc[4][6];
#pragma unroll
  for (int i = 0; i < 4; i++)
#pragma unroll
    for (int j = 0; j < 6; j++) acc[i][j] = f32x4{0.f, 0.f, 0.f, 0.f};

  auto stage = [&](int buf, int kt) {
#pragma unroll
    for (int i = 0; i < 4; ++i) {
      const int c = wv * 4 + i;                  // 32 chunks: 8 A + 24 B
      const int rr = (ln >> 2);
      const int col = kt * 32 + ((ln & 3) << 3);
      if (c < 8)
        gld16(A + (size_t)(m0 + (c << 4) + rr) * K + col, (char*)a_sm[buf] + c * 1024);
      else
        gld16(Bt + (size_t)(((c - 8) << 4) + rr) * K + col, (char*)b_sm[buf] + (c - 8) * 1024);
    }
  };

  stage(0, 0);
  __syncthreads();
  const int nk = K >> 5;
  for (int kt = 0; kt < nk; ++kt) {
    const int cur = kt & 1;
    if (kt + 1 < nk) stage(cur ^ 1, kt + 1);
    short8 af[4], bfr[6];
#pragma unroll
    for (int mi = 0; mi < 4; mi++)
      af[mi] = *(const short8*)&a_sm[cur][(wr * 64 + mi * 16 + fr) * 32 + fc];
#pragma unroll
    for (int ni = 0; ni < 6; ni++)
      bfr[ni] = *(const short8*)&b_sm[cur][(wc * 96 + ni * 16 + fr) * 32 + fc];
#pragma unroll
    for (int mi = 0; mi < 4; mi++)
#pragma unroll
      for (int ni = 0; ni < 6; ni++)
        acc[mi][ni] = __builtin_amdgcn_mfma_f32_16x16x32_bf16(af[mi], bfr[ni], acc[mi][ni], 0, 0, 0);
    __syncthreads();
  }

  const int rq = (ln >> 4) << 2;
  // v = acc + bias[col] + res[row,col]
#pragma unroll
  for (int mi = 0; mi < 4; mi++) {
    const int row = wr * 64 + mi * 16 + rq;
#pragma unroll
    for (int ni = 0; ni < 6; ni++) {
      const int col = wc * 96 + ni * 16 + fr;
      const float bv = bias[col];
#pragma unroll
      for (int r = 0; r < 4; r++)
        acc[mi][ni][r] += bv + res[(size_t)(m0 + row + r) * 384 + col];
    }
  }

  if (LN) {
    // per-row mean/var across the whole 384-wide row (4 wave-columns)
#pragma unroll
    for (int mi = 0; mi < 4; mi++) {
      float s[4] = {0.f, 0.f, 0.f, 0.f}, ss[4] = {0.f, 0.f, 0.f, 0.f};
#pragma unroll
      for (int ni = 0; ni < 6; ni++)
#pragma unroll
        for (int r = 0; r < 4; r++) {
          const float v = acc[mi][ni][r];
          s[r] += v; ss[r] += v * v;
        }
#pragma unroll
      for (int m = 1; m < 16; m <<= 1)
#pragma unroll
        for (int r = 0; r < 4; r++) {
          s[r] += __shfl_xor(s[r], m);
          ss[r] += __shfl_xor(ss[r], m);
        }
      if (fr == 0) {
#pragma unroll
        for (int r = 0; r < 4; r++) {
          lnp[wc][wr * 64 + mi * 16 + rq + r][0] = s[r];
          lnp[wc][wr * 64 + mi * 16 + rq + r][1] = ss[r];
        }
      }
    }
    __syncthreads();
#pragma unroll
    for (int mi = 0; mi < 4; mi++) {
#pragma unroll
      for (int r = 0; r < 4; r++) {
        const int row = wr * 64 + mi * 16 + rq + r;
        const float sm = lnp[0][row][0] + lnp[1][row][0] + lnp[2][row][0] + lnp[3][row][0];
        const float sq = lnp[0][row][1] + lnp[1][row][1] + lnp[2][row][1] + lnp[3][row][1];
        const float mean = sm * (1.f / 384.f);
        const float rs = rsqrtf(sq * (1.f / 384.f) - mean * mean + 1e-5f);
#pragma unroll
        for (int ni = 0; ni < 6; ni++) {
          const int col = wc * 96 + ni * 16 + fr;
          ((bfu*)Cout)[(size_t)(m0 + row) * 384 + col] =
              f2bf((acc[mi][ni][r] - mean) * rs * g[col] + be[col]);
        }
      }
    }
  } else {
#pragma unroll
    for (int mi = 0; mi < 4; mi++) {
      const int row = wr * 64 + mi * 16 + rq;
#pragma unroll
      for (int ni = 0; ni < 6; ni++) {
        const int col = wc * 96 + ni * 16 + fr;
#pragma unroll
        for (int r = 0; r < 4; r++)
          ((float*)Cout)[(size_t)(m0 + row + r) * 384 + col] = acc[mi][ni][r];
      }
    }
  }
}

// ---------------- fused causal attention: 1 block per (b,h), 8 waves --------
#define KPAD 72
#define VPAD 264
#define PPAD 264

__launch_bounds__(512)
__global__ void attn_kernel(const bfu* __restrict__ qkv, bfu* __restrict__ ob) {
  __shared__ bfu k_sm[256 * KPAD];
  __shared__ bfu vt_sm[64 * VPAD];
  __shared__ bfu p_sm[8 * 16 * PPAD];
  const int b = blockIdx.x / 6, h = blockIdx.x - b * 6;
  const int tid = threadIdx.x;
  const int wv = tid >> 6, ln = tid & 63;
  const int fr = ln & 15, fc = (ln >> 4) << 3;
  const size_t inbase = (size_t)b * 256 * 1152 + h * 64;  // qkv row stride 1152
  const bfu* qb = qkv + inbase;
  const bfu* kb = qkv + inbase + 384;
  const bfu* vb = qkv + inbase + 768;
  const size_t obase = (size_t)b * 256 * 384 + h * 64;

  {  // stage K row-major (padded) and V transposed (padded)
    const int row = tid >> 1;
    const int dh = (tid & 1) << 5;
    const bfu* kg = kb + (size_t)row * 1152 + dh;
    const bfu* vg = vb + (size_t)row * 1152 + dh;
#pragma unroll
    for (int i = 0; i < 4; i++) {
      short8 t8 = *(const short8*)(kg + i * 8);
      *(short8*)&k_sm[row * KPAD + dh + i * 8] = t8;
      short8 v8 = *(const short8*)(vg + i * 8);
#pragma unroll
      for (int j = 0; j < 8; j++)
        vt_sm[(dh + i * 8 + j) * VPAD + row] = (bfu)v8[j];
    }
  }
  __syncthreads();

  bfu* pw = &p_sm[wv * 16 * PPAD];
  const int rq = (ln >> 4) << 2;

#pragma unroll
  for (int si = 0; si < 2; ++si) {
    const int s = si ? (15 - wv) : wv;    // balanced causal work: {w, 15-w}
    const int qr0 = s << 4;
    const int nf = s + 1;                 // kv fragments needed (causal)
    short8 aq[2];
#pragma unroll
    for (int dc = 0; dc < 2; dc++)
      aq[dc] = *(const short8*)(qb + (size_t)(qr0 + fr) * 1152 + dc * 32 + fc);

    f32x4 sacc[16];
#pragma unroll
    for (int f = 0; f < 16; f++) sacc[f] = f32x4{0.f, 0.f, 0.f, 0.f};
#pragma unroll
    for (int f = 0; f < 16; f++) if (f < nf) {
#pragma unroll
      for (int dc = 0; dc < 2; dc++) {
        short8 kf = *(const short8*)&k_sm[(f * 16 + fr) * KPAD + dc * 32 + fc];
        sacc[f] = __builtin_amdgcn_mfma_f32_16x16x32_bf16(aq[dc], kf, sacc[f], 0, 0, 0);
      }
    }
    float mr[4] = {-3e38f, -3e38f, -3e38f, -3e38f};
#pragma unroll
    for (int f = 0; f < 16; f++) if (f < nf) {
#pragma unroll
      for (int r = 0; r < 4; r++) {
        float sv = sacc[f][r] * 0.125f;
        if (f * 16 + fr > qr0 + rq + r) sv = -3e38f;
        sacc[f][r] = sv;
        mr[r] = fmaxf(mr[r], sv);
      }
    }
#pragma unroll
    for (int msk = 1; msk < 16; msk <<= 1) {
#pragma unroll
      for (int r = 0; r < 4; r++) mr[r] = fmaxf(mr[r], __shfl_xor(mr[r], msk));
    }
    float ls[4] = {0.f, 0.f, 0.f, 0.f};
#pragma unroll
    for (int f = 0; f < 16; f++) if (f < nf) {
#pragma unroll
      for (int r = 0; r < 4; r++) {
        float p = __expf(sacc[f][r] - mr[r]);
        sacc[f][r] = p;
        ls[r] += p;
      }
    }
#pragma unroll
    for (int msk = 1; msk < 16; msk <<= 1) {
#pragma unroll
      for (int r = 0; r < 4; r++) ls[r] += __shfl_xor(ls[r], msk);
    }
#pragma unroll
    for (int f = 0; f < 16; f++) if (f < nf) {
#pragma unroll
      for (int r = 0; r < 4; r++)
        pw[(rq + r) * PPAD + f * 16 + fr] = f2bf(sacc[f][r]);
    }
    if (nf & 1) {
#pragma unroll
      for (int r = 0; r < 4; r++) pw[(rq + r) * PPAD + nf * 16 + fr] = 0;
    }
    f32x4 oc[4];
#pragma unroll
    for (int n = 0; n < 4; n++) oc[n] = f32x4{0.f, 0.f, 0.f, 0.f};
    const int kcs = (nf + 1) >> 1;
#pragma unroll
    for (int kc = 0; kc < 8; ++kc) if (kc < kcs) {
      short8 pa = *(const short8*)&pw[fr * PPAD + kc * 32 + fc];
#pragma unroll
      for (int n = 0; n < 4; n++) {
        short8 vf = *(const short8*)&vt_sm[(n * 16 + fr) * VPAD + kc * 32 + fc];
        oc[n] = __builtin_amdgcn_mfma_f32_16x16x32_bf16(pa, vf, oc[n], 0, 0, 0);
      }
    }
    float inv[4];
#pragma unroll
    for (int r = 0; r < 4; r++) inv[r] = 1.f / ls[r];
#pragma unroll
    for (int n = 0; n < 4; n++) {
#pragma unroll
      for (int r = 0; r < 4; r++)
        ob[obase + (size_t)(qr0 + rq + r) * 384 + n * 16 + fr] = f2bf(oc[n][r] * inv[r]);
    }
  }
}

// ---------------- orchestration ---------------------------------------------
extern "C" void kernel_launch(void* const* d_in, const int* in_sizes, int n_in,
                              void* d_out, int out_size, void* d_ws, size_t ws_size,
                              hipStream_t stream) {
  const float* x   = (const float*)d_in[0];
  const float* Wq  = (const float*)d_in[1];
  const float* Wk  = (const float*)d_in[2];
  const float* Wv  = (const float*)d_in[3];
  const float* Wo  = (const float*)d_in[4];
  const float* bo  = (const float*)d_in[5];
  const float* W1  = (const float*)d_in[6];
  const float* b1  = (const float*)d_in[7];
  const float* W2  = (const float*)d_in[8];
  const float* b2  = (const float*)d_in[9];
  const float* g1  = (const float*)d_in[10];
  const float* be1 = (const float*)d_in[11];
  const float* g2  = (const float*)d_in[12];
  const float* be2 = (const float*)d_in[13];
  float* out = (float*)d_out;
  char* ws = (char*)d_ws;

  // workspace layout (255.2 MB total; phases strictly ordered on the stream)
  bfu* wqkvT = (bfu*)(ws + 0);          // 1152x384 bf16 = 884736 B
  bfu* woT   = (bfu*)(ws + 884736);     // 294912
  bfu* w1T   = (bfu*)(ws + 1179648);    // 1179648
  bfu* w2T   = (bfu*)(ws + 2359296);    // 1179648
  char* H    = ws + 3538944;            // 50.3 MB: h2
  char* BIG  = H + 50331648;            // 201.3 MB: {h | attn} + qkv -> ab
  bfu* hb    = (bfu*)BIG;               // 50.3 MB (dead after QKV gemm)
  bfu* qkvb  = (bfu*)(BIG + 50331648);  // 151 MB (dead after attention)
  bfu* attnb = (bfu*)BIG;               // reuses hb region
  bfu* h2b   = (bfu*)H;
  bfu* ab    = (bfu*)BIG;               // 201.3 MB (clobbers attnb+qkvb, both dead)

  // 1) weights -> bf16 transposed (Wq/Wk/Wv packed into one [1152][384])
  transpose_w<<<576, 256, 0, stream>>>(Wq, wqkvT, 384, 384);
  transpose_w<<<576, 256, 0, stream>>>(Wk, wqkvT + 384 * 384, 384, 384);
  transpose_w<<<576, 256, 0, stream>>>(Wv, wqkvT + 2 * 384 * 384, 384, 384);
  transpose_w<<<576, 256, 0, stream>>>(Wo, woT, 384, 384);
  transpose_w<<<2304, 256, 0, stream>>>(W1, w1T, 384, 1536);
  transpose_w<<<2304, 256, 0, stream>>>(W2, w2T, 1536, 384);

  // 2) LN1
  ln_kernel<<<16384, 256, 0, stream>>>(x, g1, be1, hb);

  // 3) fused QKV GEMM (N=1152, bf16 out)
  gemm_kernel<0, 0, 1><<<4608, 256, 0, stream>>>(hb, wqkvT, nullptr, qkvb, 1152, 384, 9);

  // 4) fused causal attention (reads packed qkv, stride 1152)
  attn_kernel<<<1536, 512, 0, stream>>>(qkvb, attnb);

  // 5) proj + bias + residual(x) + LN2 fused -> h2 (bf16)
  row_gemm<1><<<512, 512, 0, stream>>>(attnb, woT, bo, x, g2, be2, h2b, 384);

  // 6) FFN1 (+bias+ReLU, bf16 out)
  gemm_kernel<1, 1, 1><<<6144, 256, 0, stream>>>(h2b, w1T, b1, ab, 1536, 384, 12);

  // 7) FFN2 + bias + residual(x) -> out (fp32)
  row_gemm<0><<<512, 512, 0, stream>>>(ab, w2T, b2, x, nullptr, nullptr, out, 1536);
}

// Round 3
// 521.160 us; speedup vs baseline: 1.2027x; 1.0319x over previous
//
#include <hip/hip_runtime.h>
#include <hip/hip_bf16.h>

typedef unsigned short bfu;
typedef __attribute__((ext_vector_type(8))) short short8;
typedef __attribute__((ext_vector_type(4))) float f32x4;

__device__ __forceinline__ bfu f2bf(float f) {
  return __builtin_bit_cast(bfu, __float2bfloat16(f));
}

__device__ __forceinline__ void gld16(const void* g, void* l) {
  __builtin_amdgcn_global_load_lds(
      (const __attribute__((address_space(1))) void*)g,
      (__attribute__((address_space(3))) void*)l, 16, 0, 0);
}

// ---------------- weight transpose + bf16 cast: WT[n][k] = W[k][n] ----------
__global__ void transpose_w(const float* __restrict__ W, bfu* __restrict__ WT,
                            int K, int N) {
  int idx = blockIdx.x * 256 + threadIdx.x;
  if (idx >= K * N) return;
  int k = idx / N, n = idx - k * N;
  WT[(size_t)n * K + k] = f2bf(W[idx]);
}

// ---------------- LayerNorm: one wave per row of 384 ------------------------
__launch_bounds__(256)
__global__ void ln_kernel(const float* __restrict__ in, const float* __restrict__ g,
                          const float* __restrict__ be, bfu* __restrict__ out) {
  const int wv = threadIdx.x >> 6, ln = threadIdx.x & 63;
  const size_t row = (size_t)blockIdx.x * 4 + wv;
  const float* p = in + row * 384;
  float v[6], s = 0.f, ss = 0.f;
#pragma unroll
  for (int i = 0; i < 6; i++) { v[i] = p[i * 64 + ln]; s += v[i]; ss += v[i] * v[i]; }
#pragma unroll
  for (int m = 1; m < 64; m <<= 1) { s += __shfl_xor(s, m); ss += __shfl_xor(ss, m); }
  const float mean = s * (1.f / 384.f);
  const float rs = rsqrtf(ss * (1.f / 384.f) - mean * mean + 1e-5f);
  bfu* q = out + row * 384;
#pragma unroll
  for (int i = 0; i < 6; i++) {
    const int c = i * 64 + ln;
    q[c] = f2bf((v[i] - mean) * rs * g[c] + be[c]);
  }
}

// ---------------- GEMM: C[M,N] = A[M,K](bf16) @ BT[N,K](bf16)^T -------------
// 128x128 tile, BK=32, 4 waves (2x2). 3-buffer ring, ONE raw s_barrier per
// K-step, counted vmcnt so prefetch loads stay in flight across barriers.
template <int BIAS, int RELU, int OUTBF>
__launch_bounds__(256)
__global__ void gemm_kernel(const bfu* __restrict__ A, const bfu* __restrict__ Bt,
                            const float* __restrict__ bias,
                            void* __restrict__ Cout, int N, int K, int ntn) {
  __shared__ bfu a_sm[3][128 * 32];
  __shared__ bfu b_sm[3][128 * 32];
  const int tid = threadIdx.x;
  const int wv = tid >> 6, ln = tid & 63;
  const int cpx = gridDim.x >> 3;
  const int wg = (blockIdx.x & 7) * cpx + (blockIdx.x >> 3);
  const int bm = wg / ntn, bn = wg - bm * ntn;
  const int m0 = bm << 7, n0 = bn << 7;
  const int wr = wv >> 1, wc = wv & 1;
  const int fr = ln & 15, fc = (ln >> 4) << 3;

  f32x4 acc[4][4];
#pragma unroll
  for (int i = 0; i < 4; i++)
#pragma unroll
    for (int j = 0; j < 4; j++) acc[i][j] = f32x4{0.f, 0.f, 0.f, 0.f};

  auto stage = [&](int buf, int kt) {
#pragma unroll
    for (int i = 0; i < 2; ++i) {
      const int c = wv * 2 + i;                    // chunk 0..7 (1 KB each)
      const int r = (c << 4) + (ln >> 2);          // 16 rows per chunk
      const int col = kt * 32 + ((ln & 3) << 3);
      gld16(A  + (size_t)(m0 + r) * K + col, (char*)a_sm[buf] + c * 1024);
      gld16(Bt + (size_t)(n0 + r) * K + col, (char*)b_sm[buf] + c * 1024);
    }
  };

  const int nk = K >> 5;
  stage(0, 0);
  if (nk > 1) stage(1, 1);

  int cb = 0;
  for (int kt = 0; kt < nk; ++kt) {
    // drain own loads of tile kt; leave tile kt+1's (4) in flight
    if (kt + 1 < nk) asm volatile("s_waitcnt vmcnt(4)" ::: "memory");
    else             asm volatile("s_waitcnt vmcnt(0)" ::: "memory");
    __builtin_amdgcn_s_barrier();
    __builtin_amdgcn_sched_barrier(0);
    if (kt + 2 < nk) {
      int sb = cb + 2; if (sb >= 3) sb -= 3;
      stage(sb, kt + 2);
    }
    short8 af[4], bfr[4];
#pragma unroll
    for (int mi = 0; mi < 4; mi++)
      af[mi] = *(const short8*)&a_sm[cb][(wr * 64 + mi * 16 + fr) * 32 + fc];
#pragma unroll
    for (int ni = 0; ni < 4; ni++)
      bfr[ni] = *(const short8*)&b_sm[cb][(wc * 64 + ni * 16 + fr) * 32 + fc];
#pragma unroll
    for (int mi = 0; mi < 4; mi++)
#pragma unroll
      for (int ni = 0; ni < 4; ni++)
        acc[mi][ni] = __builtin_amdgcn_mfma_f32_16x16x32_bf16(af[mi], bfr[ni], acc[mi][ni], 0, 0, 0);
    cb = (cb + 1 == 3) ? 0 : cb + 1;
  }

#pragma unroll
  for (int mi = 0; mi < 4; mi++) {
#pragma unroll
    for (int ni = 0; ni < 4; ni++) {
      const int row = m0 + wr * 64 + mi * 16 + ((ln >> 4) << 2);
      const int col = n0 + wc * 64 + ni * 16 + fr;
      float bv = 0.f;
      if (BIAS) bv = bias[col];
#pragma unroll
      for (int r = 0; r < 4; r++) {
        float v = acc[mi][ni][r] + bv;
        if (RELU) v = fmaxf(v, 0.f);
        const size_t idx = (size_t)(row + r) * N + col;
        if (OUTBF) ((bfu*)Cout)[idx] = f2bf(v);
        else       ((float*)Cout)[idx] = v;
      }
    }
  }
}

// ---------------- full-row GEMM: C[M,384] = A[M,K] @ Bt[384,K]^T ------------
// BM=128, BN=384, 8 waves (2x4, 64x96 each), BK=32. 4-buffer ring (prefetch
// depth 3), one raw s_barrier + counted vmcnt per K-step. Epilogue: +bias
// +residual, then LN (LN=1, bf16 out) or plain fp32 out (LN=0).
template <int LN>
__launch_bounds__(512)
__global__ void row_gemm(const bfu* __restrict__ A, const bfu* __restrict__ Bt,
                         const float* __restrict__ bias, const float* __restrict__ res,
                         const float* __restrict__ g, const float* __restrict__ be,
                         void* __restrict__ Cout, int K) {
  __shared__ bfu a_sm[4][128 * 32];
  __shared__ bfu b_sm[4][384 * 32];
  __shared__ float lnp[4][128][2];
  const int tid = threadIdx.x;
  const int wv = tid >> 6, ln = tid & 63;
  const int wr = wv >> 2, wc = wv & 3;          // 2 x 4 wave grid
  const int fr = ln & 15, fc = (ln >> 4) << 3;
  const int m0 = blockIdx.x << 7;

  f32x4 acc[4][6];
#pragma unroll
  for (int i = 0; i < 4; i++)
#pragma unroll
    for (int j = 0; j < 6; j++) acc[i][j] = f32x4{0.f, 0.f, 0.f, 0.f};

  auto stage = [&](int buf, int kt) {
#pragma unroll
    for (int i = 0; i < 4; ++i) {
      const int c = wv * 4 + i;                  // 32 chunks: 8 A + 24 B
      const int rr = (ln >> 2);
      const int col = kt * 32 + ((ln & 3) << 3);
      if (c < 8)
        gld16(A + (size_t)(m0 + (c << 4) + rr) * K + col, (char*)a_sm[buf] + c * 1024);
      else
        gld16(Bt + (size_t)(((c - 8) << 4) + rr) * K + col, (char*)b_sm[buf] + (c - 8) * 1024);
    }
  };

  const int nk = K >> 5;
#pragma unroll
  for (int i = 0; i < 3; ++i)
    if (i < nk) stage(i, i);

  for (int kt = 0; kt < nk; ++kt) {
    const int rem = nk - 1 - kt;   // tiles staged beyond kt
    if (rem >= 2)      asm volatile("s_waitcnt vmcnt(8)" ::: "memory");
    else if (rem == 1) asm volatile("s_waitcnt vmcnt(4)" ::: "memory");
    else               asm volatile("s_waitcnt vmcnt(0)" ::: "memory");
    __builtin_amdgcn_s_barrier();
    __builtin_amdgcn_sched_barrier(0);
    if (kt + 3 < nk) stage((kt + 3) & 3, kt + 3);
    const int cb = kt & 3;
    short8 af[4], bfr[6];
#pragma unroll
    for (int mi = 0; mi < 4; mi++)
      af[mi] = *(const short8*)&a_sm[cb][(wr * 64 + mi * 16 + fr) * 32 + fc];
#pragma unroll
    for (int ni = 0; ni < 6; ni++)
      bfr[ni] = *(const short8*)&b_sm[cb][(wc * 96 + ni * 16 + fr) * 32 + fc];
#pragma unroll
    for (int mi = 0; mi < 4; mi++)
#pragma unroll
      for (int ni = 0; ni < 6; ni++)
        acc[mi][ni] = __builtin_amdgcn_mfma_f32_16x16x32_bf16(af[mi], bfr[ni], acc[mi][ni], 0, 0, 0);
  }

  const int rq = (ln >> 4) << 2;
#pragma unroll
  for (int mi = 0; mi < 4; mi++) {
    const int row = wr * 64 + mi * 16 + rq;
#pragma unroll
    for (int ni = 0; ni < 6; ni++) {
      const int col = wc * 96 + ni * 16 + fr;
      const float bv = bias[col];
#pragma unroll
      for (int r = 0; r < 4; r++)
        acc[mi][ni][r] += bv + res[(size_t)(m0 + row + r) * 384 + col];
    }
  }

  if (LN) {
#pragma unroll
    for (int mi = 0; mi < 4; mi++) {
      float s[4] = {0.f, 0.f, 0.f, 0.f}, ss[4] = {0.f, 0.f, 0.f, 0.f};
#pragma unroll
      for (int ni = 0; ni < 6; ni++)
#pragma unroll
        for (int r = 0; r < 4; r++) {
          const float v = acc[mi][ni][r];
          s[r] += v; ss[r] += v * v;
        }
#pragma unroll
      for (int m = 1; m < 16; m <<= 1)
#pragma unroll
        for (int r = 0; r < 4; r++) {
          s[r] += __shfl_xor(s[r], m);
          ss[r] += __shfl_xor(ss[r], m);
        }
      if (fr == 0) {
#pragma unroll
        for (int r = 0; r < 4; r++) {
          lnp[wc][wr * 64 + mi * 16 + rq + r][0] = s[r];
          lnp[wc][wr * 64 + mi * 16 + rq + r][1] = ss[r];
        }
      }
    }
    __syncthreads();
#pragma unroll
    for (int mi = 0; mi < 4; mi++) {
#pragma unroll
      for (int r = 0; r < 4; r++) {
        const int row = wr * 64 + mi * 16 + rq + r;
        const float sm = lnp[0][row][0] + lnp[1][row][0] + lnp[2][row][0] + lnp[3][row][0];
        const float sq = lnp[0][row][1] + lnp[1][row][1] + lnp[2][row][1] + lnp[3][row][1];
        const float mean = sm * (1.f / 384.f);
        const float rs = rsqrtf(sq * (1.f / 384.f) - mean * mean + 1e-5f);
#pragma unroll
        for (int ni = 0; ni < 6; ni++) {
          const int col = wc * 96 + ni * 16 + fr;
          ((bfu*)Cout)[(size_t)(m0 + row) * 384 + col] =
              f2bf((acc[mi][ni][r] - mean) * rs * g[col] + be[col]);
        }
      }
    }
  } else {
#pragma unroll
    for (int mi = 0; mi < 4; mi++) {
      const int row = wr * 64 + mi * 16 + rq;
#pragma unroll
      for (int ni = 0; ni < 6; ni++) {
        const int col = wc * 96 + ni * 16 + fr;
#pragma unroll
        for (int r = 0; r < 4; r++)
          ((float*)Cout)[(size_t)(m0 + row + r) * 384 + col] = acc[mi][ni][r];
      }
    }
  }
}

// ---------------- fused causal attention: 1 block per (b,h), 8 waves --------
#define KPAD 72
#define VPAD 264
#define PPAD 264

__launch_bounds__(512)
__global__ void attn_kernel(const bfu* __restrict__ qkv, bfu* __restrict__ ob) {
  __shared__ bfu k_sm[256 * KPAD];
  __shared__ bfu vt_sm[64 * VPAD];
  __shared__ bfu p_sm[8 * 16 * PPAD];
  const int b = blockIdx.x / 6, h = blockIdx.x - b * 6;
  const int tid = threadIdx.x;
  const int wv = tid >> 6, ln = tid & 63;
  const int fr = ln & 15, fc = (ln >> 4) << 3;
  const size_t inbase = (size_t)b * 256 * 1152 + h * 64;  // qkv row stride 1152
  const bfu* qb = qkv + inbase;
  const bfu* kb = qkv + inbase + 384;
  const bfu* vb = qkv + inbase + 768;
  const size_t obase = (size_t)b * 256 * 384 + h * 64;

  {  // stage K row-major (padded) and V transposed (padded)
    const int row = tid >> 1;
    const int dh = (tid & 1) << 5;
    const bfu* kg = kb + (size_t)row * 1152 + dh;
    const bfu* vg = vb + (size_t)row * 1152 + dh;
#pragma unroll
    for (int i = 0; i < 4; i++) {
      short8 t8 = *(const short8*)(kg + i * 8);
      *(short8*)&k_sm[row * KPAD + dh + i * 8] = t8;
      short8 v8 = *(const short8*)(vg + i * 8);
#pragma unroll
      for (int j = 0; j < 8; j++)
        vt_sm[(dh + i * 8 + j) * VPAD + row] = (bfu)v8[j];
    }
  }
  __syncthreads();

  bfu* pw = &p_sm[wv * 16 * PPAD];
  const int rq = (ln >> 4) << 2;

#pragma unroll
  for (int si = 0; si < 2; ++si) {
    const int s = si ? (15 - wv) : wv;    // balanced causal work: {w, 15-w}
    const int qr0 = s << 4;
    const int nf = s + 1;                 // kv fragments needed (causal)
    short8 aq[2];
#pragma unroll
    for (int dc = 0; dc < 2; dc++)
      aq[dc] = *(const short8*)(qb + (size_t)(qr0 + fr) * 1152 + dc * 32 + fc);

    f32x4 sacc[16];
#pragma unroll
    for (int f = 0; f < 16; f++) sacc[f] = f32x4{0.f, 0.f, 0.f, 0.f};
#pragma unroll
    for (int f = 0; f < 16; f++) if (f < nf) {
#pragma unroll
      for (int dc = 0; dc < 2; dc++) {
        short8 kf = *(const short8*)&k_sm[(f * 16 + fr) * KPAD + dc * 32 + fc];
        sacc[f] = __builtin_amdgcn_mfma_f32_16x16x32_bf16(aq[dc], kf, sacc[f], 0, 0, 0);
      }
    }
    float mr[4] = {-3e38f, -3e38f, -3e38f, -3e38f};
#pragma unroll
    for (int f = 0; f < 16; f++) if (f < nf) {
#pragma unroll
      for (int r = 0; r < 4; r++) {
        float sv = sacc[f][r] * 0.125f;
        if (f * 16 + fr > qr0 + rq + r) sv = -3e38f;
        sacc[f][r] = sv;
        mr[r] = fmaxf(mr[r], sv);
      }
    }
#pragma unroll
    for (int msk = 1; msk < 16; msk <<= 1) {
#pragma unroll
      for (int r = 0; r < 4; r++) mr[r] = fmaxf(mr[r], __shfl_xor(mr[r], msk));
    }
    float ls[4] = {0.f, 0.f, 0.f, 0.f};
#pragma unroll
    for (int f = 0; f < 16; f++) if (f < nf) {
#pragma unroll
      for (int r = 0; r < 4; r++) {
        float p = __expf(sacc[f][r] - mr[r]);
        sacc[f][r] = p;
        ls[r] += p;
      }
    }
#pragma unroll
    for (int msk = 1; msk < 16; msk <<= 1) {
#pragma unroll
      for (int r = 0; r < 4; r++) ls[r] += __shfl_xor(ls[r], msk);
    }
#pragma unroll
    for (int f = 0; f < 16; f++) if (f < nf) {
#pragma unroll
      for (int r = 0; r < 4; r++)
        pw[(rq + r) * PPAD + f * 16 + fr] = f2bf(sacc[f][r]);
    }
    if (nf & 1) {
#pragma unroll
      for (int r = 0; r < 4; r++) pw[(rq + r) * PPAD + nf * 16 + fr] = 0;
    }
    f32x4 oc[4];
#pragma unroll
    for (int n = 0; n < 4; n++) oc[n] = f32x4{0.f, 0.f, 0.f, 0.f};
    const int kcs = (nf + 1) >> 1;
#pragma unroll
    for (int kc = 0; kc < 8; ++kc) if (kc < kcs) {
      short8 pa = *(const short8*)&pw[fr * PPAD + kc * 32 + fc];
#pragma unroll
      for (int n = 0; n < 4; n++) {
        short8 vf = *(const short8*)&vt_sm[(n * 16 + fr) * VPAD + kc * 32 + fc];
        oc[n] = __builtin_amdgcn_mfma_f32_16x16x32_bf16(pa, vf, oc[n], 0, 0, 0);
      }
    }
    float inv[4];
#pragma unroll
    for (int r = 0; r < 4; r++) inv[r] = 1.f / ls[r];
#pragma unroll
    for (int n = 0; n < 4; n++) {
#pragma unroll
      for (int r = 0; r < 4; r++)
        ob[obase + (size_t)(qr0 + rq + r) * 384 + n * 16 + fr] = f2bf(oc[n][r] * inv[r]);
    }
  }
}

// ---------------- orchestration ---------------------------------------------
extern "C" void kernel_launch(void* const* d_in, const int* in_sizes, int n_in,
                              void* d_out, int out_size, void* d_ws, size_t ws_size,
                              hipStream_t stream) {
  const float* x   = (const float*)d_in[0];
  const float* Wq  = (const float*)d_in[1];
  const float* Wk  = (const float*)d_in[2];
  const float* Wv  = (const float*)d_in[3];
  const float* Wo  = (const float*)d_in[4];
  const float* bo  = (const float*)d_in[5];
  const float* W1  = (const float*)d_in[6];
  const float* b1  = (const float*)d_in[7];
  const float* W2  = (const float*)d_in[8];
  const float* b2  = (const float*)d_in[9];
  const float* g1  = (const float*)d_in[10];
  const float* be1 = (const float*)d_in[11];
  const float* g2  = (const float*)d_in[12];
  const float* be2 = (const float*)d_in[13];
  float* out = (float*)d_out;
  char* ws = (char*)d_ws;

  // workspace layout (255.2 MB total; phases strictly ordered on the stream)
  bfu* wqkvT = (bfu*)(ws + 0);          // 1152x384 bf16 = 884736 B
  bfu* woT   = (bfu*)(ws + 884736);     // 294912
  bfu* w1T   = (bfu*)(ws + 1179648);    // 1179648
  bfu* w2T   = (bfu*)(ws + 2359296);    // 1179648
  char* H    = ws + 3538944;            // 50.3 MB: h2
  char* BIG  = H + 50331648;            // 201.3 MB: {h | attn} + qkv -> ab
  bfu* hb    = (bfu*)BIG;               // 50.3 MB (dead after QKV gemm)
  bfu* qkvb  = (bfu*)(BIG + 50331648);  // 151 MB (dead after attention)
  bfu* attnb = (bfu*)BIG;               // reuses hb region
  bfu* h2b   = (bfu*)H;
  bfu* ab    = (bfu*)BIG;               // 201.3 MB (clobbers attnb+qkvb, both dead)

  // 1) weights -> bf16 transposed (Wq/Wk/Wv packed into one [1152][384])
  transpose_w<<<576, 256, 0, stream>>>(Wq, wqkvT, 384, 384);
  transpose_w<<<576, 256, 0, stream>>>(Wk, wqkvT + 384 * 384, 384, 384);
  transpose_w<<<576, 256, 0, stream>>>(Wv, wqkvT + 2 * 384 * 384, 384, 384);
  transpose_w<<<576, 256, 0, stream>>>(Wo, woT, 384, 384);
  transpose_w<<<2304, 256, 0, stream>>>(W1, w1T, 384, 1536);
  transpose_w<<<2304, 256, 0, stream>>>(W2, w2T, 1536, 384);

  // 2) LN1
  ln_kernel<<<16384, 256, 0, stream>>>(x, g1, be1, hb);

  // 3) fused QKV GEMM (N=1152, bf16 out)
  gemm_kernel<0, 0, 1><<<4608, 256, 0, stream>>>(hb, wqkvT, nullptr, qkvb, 1152, 384, 9);

  // 4) fused causal attention (reads packed qkv, stride 1152)
  attn_kernel<<<1536, 512, 0, stream>>>(qkvb, attnb);

  // 5) proj + bias + residual(x) + LN2 fused -> h2 (bf16)
  row_gemm<1><<<512, 512, 0, stream>>>(attnb, woT, bo, x, g2, be2, h2b, 384);

  // 6) FFN1 (+bias+ReLU, bf16 out)
  gemm_kernel<1, 1, 1><<<6144, 256, 0, stream>>>(h2b, w1T, b1, ab, 1536, 384, 12);

  // 7) FFN2 + bias + residual(x) -> out (fp32)
  row_gemm<0><<<512, 512, 0, stream>>>(ab, w2T, b2, x, nullptr, nullptr, out, 1536);
}